// Round 1
// baseline (473.815 us; speedup 1.0000x reference)
//
#include <hip/hip_runtime.h>
#include <hip/hip_bf16.h>
#include <math.h>

#define B_ 128
#define H_ 100
#define C_ 32
#define K_ 4
#define D_ 400
#define E_ 200
#define CW_ 100
#define N_ (B_*C_)

// ------------------------------------------------------------------
// k1: per-channel additive attention logits.
// logits[(b*K+k)*H+h] = sum_e tanh( sum_d his[b,h,k,d]*W_att[k,d,e] + b_att[k,e] ) * q_att[k,e]
// GEMM per k: M=B*H=12800 rows, N=E=200 (padded to 256), Kdim=D=400.
// Block = 256 thr = (tr 0..7 rows-groups) x (tc 0..31 col-groups); BM=64, BD=16.
// Per-thread tile 8 rows x 8 cols (cols = 4*tc..+3 and 128+4*tc..+3).
// LDS: A [64][21] (stride-21: 2-way bank alias = free), W [16][256] float4 reads.
// ------------------------------------------------------------------
__global__ __launch_bounds__(256) void k1_att(const float* __restrict__ his,
                                              const float* __restrict__ W_att,
                                              const float* __restrict__ b_att,
                                              const float* __restrict__ q_att,
                                              float* __restrict__ logits) {
  const int mt = blockIdx.x;          // 0..199
  const int k  = blockIdx.y;          // 0..3
  const int tid = threadIdx.x;
  const int tr = tid >> 5;            // 0..7
  const int tc = tid & 31;            // 0..31
  __shared__ float Al[64][21];
  __shared__ float Wl[16][256];

  float acc[8][8];
  #pragma unroll
  for (int i = 0; i < 8; ++i)
    #pragma unroll
    for (int j = 0; j < 8; ++j) acc[i][j] = 0.f;

  // zero-fill padded W cols 200..255 once (staging only writes cols < 200)
  for (int idx = tid; idx < 16*56; idx += 256) Wl[idx/56][200 + idx%56] = 0.f;

  const int m0 = mt * 64;
  const int r  = tid >> 2;            // A-load row 0..63
  const int c4 = tid & 3;             // A-load float4 chunk

  #pragma unroll 1
  for (int d0 = 0; d0 < D_; d0 += 16) {
    __syncthreads();
    // stage A tile: 64 rows x 16 d (coalesced float4 per thread)
    {
      const float4 a4 = *(const float4*)(his + ((size_t)(m0 + r)*K_ + k)*D_ + d0 + c4*4);
      Al[r][c4*4+0] = a4.x; Al[r][c4*4+1] = a4.y;
      Al[r][c4*4+2] = a4.z; Al[r][c4*4+3] = a4.w;
    }
    // stage W tile: 16 d-rows x 200 cols (50 float4 per row)
    for (int idx = tid; idx < 16*50; idx += 256) {
      const int rw = idx / 50, cc = idx % 50;
      *(float4*)&Wl[rw][cc*4] = *(const float4*)(W_att + ((size_t)k*D_ + d0 + rw)*E_ + cc*4);
    }
    __syncthreads();
    #pragma unroll
    for (int dd = 0; dd < 16; ++dd) {
      float av[8];
      #pragma unroll
      for (int i = 0; i < 8; ++i) av[i] = Al[tr*8 + i][dd];
      const float4 w0 = *(const float4*)&Wl[dd][tc*4];
      const float4 w1 = *(const float4*)&Wl[dd][tc*4 + 128];
      #pragma unroll
      for (int i = 0; i < 8; ++i) {
        acc[i][0] += av[i]*w0.x; acc[i][1] += av[i]*w0.y;
        acc[i][2] += av[i]*w0.z; acc[i][3] += av[i]*w0.w;
        acc[i][4] += av[i]*w1.x; acc[i][5] += av[i]*w1.y;
        acc[i][6] += av[i]*w1.z; acc[i][7] += av[i]*w1.w;
      }
    }
  }

  // epilogue: tanh + dot with q_att, reduce across the 32 tc lanes
  float p[8];
  #pragma unroll
  for (int i = 0; i < 8; ++i) p[i] = 0.f;
  #pragma unroll
  for (int jj = 0; jj < 2; ++jj)
    #pragma unroll
    for (int jx = 0; jx < 4; ++jx) {
      const int e = tc*4 + jj*128 + jx;
      float q = 0.f, bb = 0.f;
      if (e < E_) { q = q_att[k*E_ + e]; bb = b_att[k*E_ + e]; }
      #pragma unroll
      for (int i = 0; i < 8; ++i) p[i] += tanhf(acc[i][jj*4 + jx] + bb) * q;
    }
  #pragma unroll
  for (int off = 16; off >= 1; off >>= 1)
    #pragma unroll
    for (int i = 0; i < 8; ++i) p[i] += __shfl_xor(p[i], off);
  if (tc == 0) {
    #pragma unroll
    for (int i = 0; i < 8; ++i) {
      const int m = m0 + tr*8 + i;
      const int b = m / H_, h = m % H_;
      logits[(b*K_ + k)*H_ + h] = p[i];
    }
  }
}

// ------------------------------------------------------------------
// k2: softmax over H per (b,k), then u_b[b,k,d] = sum_h a[h]*his[b,h,k,d]
// ------------------------------------------------------------------
__global__ __launch_bounds__(256) void k2_softmax_u(const float* __restrict__ his,
                                                    const float* __restrict__ logits,
                                                    float* __restrict__ u_b) {
  const int b = blockIdx.x, k = blockIdx.y;
  const int tid = threadIdx.x;
  __shared__ float sv[128];
  __shared__ float sa[H_];
  float v = -INFINITY;
  if (tid < H_) v = logits[(b*K_ + k)*H_ + tid];
  if (tid < 128) sv[tid] = v;
  __syncthreads();
  for (int s = 64; s > 0; s >>= 1) {
    if (tid < s) sv[tid] = fmaxf(sv[tid], sv[tid + s]);
    __syncthreads();
  }
  const float mx = sv[0];
  __syncthreads();
  float ev = 0.f;
  if (tid < H_) ev = expf(v - mx);
  if (tid < 128) sv[tid] = ev;
  __syncthreads();
  for (int s = 64; s > 0; s >>= 1) {
    if (tid < s) sv[tid] += sv[tid + s];
    __syncthreads();
  }
  const float inv = 1.f / sv[0];
  if (tid < H_) sa[tid] = ev * inv;
  __syncthreads();
  for (int d = tid; d < D_; d += 256) {
    float acc = 0.f;
    const float* hp = his + ((size_t)b*H_*K_ + k)*D_ + d;
    #pragma unroll 4
    for (int h = 0; h < H_; ++h) acc += sa[h] * hp[(size_t)h*K_*D_];
    u_b[(b*K_ + k)*D_ + d] = acc;
  }
}

// ------------------------------------------------------------------
// k3: ulin[b,k,e] = b_lin[e] + sum_d u_b[b,k,d]*W_lin[d,e]
// (the candidate-independent half of the cw @ W_lin GEMM, factored out)
// ------------------------------------------------------------------
__global__ __launch_bounds__(256) void k3_ulin(const float* __restrict__ u_b,
                                               const float* __restrict__ W_lin,
                                               const float* __restrict__ b_lin,
                                               float* __restrict__ ulin) {
  const int b = blockIdx.x, k = blockIdx.y;
  const int tid = threadIdx.x;
  __shared__ float ul[D_];
  for (int idx = tid; idx < D_; idx += 256) ul[idx] = u_b[(b*K_ + k)*D_ + idx];
  __syncthreads();
  if (tid < E_) {
    float acc = b_lin[tid];
    #pragma unroll 4
    for (int d = 0; d < D_; ++d) acc += ul[d] * W_lin[(size_t)d*E_ + tid];
    ulin[(b*K_ + k)*E_ + tid] = acc;
  }
}

// ------------------------------------------------------------------
// k4: per 8 candidates (same b): score dots, channel-weight half of the
// linear, tanh + q_vec logits, softmax over K, final scores; also writes
// u_channel (broadcast of u_b). Thread layout: pr = n-sub (0..7) owns all
// K; pc (0..31) owns cols e = pc+32j, j=0..6 (e<200 masked).
// ------------------------------------------------------------------
__global__ __launch_bounds__(256) void k4_combine(const float* __restrict__ cdd,
                                                  const float* __restrict__ cwt,
                                                  const float* __restrict__ W_lin,
                                                  const float* __restrict__ q_vec,
                                                  const float* __restrict__ u_b,
                                                  const float* __restrict__ ulin,
                                                  float* __restrict__ out) {
  const int n0 = blockIdx.x * 8;
  const int b  = n0 / C_;
  const int tid = threadIdx.x;
  const int pr = tid >> 5;
  const int pc = tid & 31;
  __shared__ float u_lds[K_*D_];
  __shared__ float cw_lds[8][K_][CW_ + 1];   // +1 pad: conflict-free broadcast
  __shared__ float sc_lds[8][K_];
  __shared__ float lg_lds[8][K_];

  for (int idx = tid; idx < K_*D_; idx += 256) u_lds[idx] = u_b[(size_t)b*K_*D_ + idx];
  {
    const float* src = cwt + (size_t)n0*K_*CW_;
    for (int idx = tid; idx < 8*K_*CW_; idx += 256) {
      const int i = idx / (K_*CW_);
      const int rem = idx % (K_*CW_);
      cw_lds[i][rem / CW_][rem % CW_] = src[idx];
    }
  }
  __syncthreads();

  // candidate scores: 32 dot-products of length D over 4 waves
  {
    const int wv = tid >> 6, ln = tid & 63;
    for (int p = wv; p < 8*K_; p += 4) {
      const int i = p >> 2, kk = p & 3;
      const float* cp = cdd + ((size_t)(n0 + i)*K_ + kk)*D_;
      float acc = 0.f;
      for (int d = ln; d < D_; d += 64) acc += u_lds[kk*D_ + d] * cp[d];
      #pragma unroll
      for (int off = 32; off >= 1; off >>= 1) acc += __shfl_down(acc, off);
      if (ln == 0) sc_lds[i][kk] = acc;
    }
  }

  // cl[kk][e] = sum_c cw[n,kk,c] * W_lin[D+c, e]  (register-tiled 4x7)
  float acc[K_][7];
  #pragma unroll
  for (int kk = 0; kk < K_; ++kk)
    #pragma unroll
    for (int j = 0; j < 7; ++j) acc[kk][j] = 0.f;

  #pragma unroll 4
  for (int c = 0; c < CW_; ++c) {
    float w[7];
    #pragma unroll
    for (int j = 0; j < 7; ++j) {
      const int e = pc + 32*j;
      w[j] = (e < E_) ? W_lin[(size_t)(D_ + c)*E_ + e] : 0.f;
    }
    #pragma unroll
    for (int kk = 0; kk < K_; ++kk) {
      const float a = cw_lds[pr][kk][c];
      #pragma unroll
      for (int j = 0; j < 7; ++j) acc[kk][j] += a * w[j];
    }
  }

  // logits: sum_e tanh(ulin + cl) * q_vec, reduced over the 32 pc lanes
  float pl[K_] = {0.f, 0.f, 0.f, 0.f};
  #pragma unroll
  for (int j = 0; j < 7; ++j) {
    const int e = pc + 32*j;
    if (e < E_) {
      const float q = q_vec[e];
      #pragma unroll
      for (int kk = 0; kk < K_; ++kk)
        pl[kk] += tanhf(ulin[((size_t)b*K_ + kk)*E_ + e] + acc[kk][j]) * q;
    }
  }
  #pragma unroll
  for (int off = 16; off >= 1; off >>= 1)
    #pragma unroll
    for (int kk = 0; kk < K_; ++kk) pl[kk] += __shfl_xor(pl[kk], off);
  if (pc == 0) {
    #pragma unroll
    for (int kk = 0; kk < K_; ++kk) lg_lds[pr][kk] = pl[kk];
  }
  __syncthreads();

  // softmax over K and final score
  if (tid < 8) {
    const float l0 = lg_lds[tid][0], l1 = lg_lds[tid][1];
    const float l2 = lg_lds[tid][2], l3 = lg_lds[tid][3];
    const float m = fmaxf(fmaxf(l0, l1), fmaxf(l2, l3));
    const float e0 = expf(l0 - m), e1 = expf(l1 - m);
    const float e2 = expf(l2 - m), e3 = expf(l3 - m);
    const float s = e0 + e1 + e2 + e3;
    out[n0 + tid] = (e0*sc_lds[tid][0] + e1*sc_lds[tid][1] +
                     e2*sc_lds[tid][2] + e3*sc_lds[tid][3]) / s;
  }

  // u_channel output (broadcast of u_b over the 8 candidates)
  float* uo = out + N_ + (size_t)n0*K_*D_;
  for (int idx = tid; idx < 8*K_*D_; idx += 256) uo[idx] = u_lds[idx % (K_*D_)];
}

extern "C" void kernel_launch(void* const* d_in, const int* in_sizes, int n_in,
                              void* d_out, int out_size, void* d_ws, size_t ws_size,
                              hipStream_t stream) {
  const float* his   = (const float*)d_in[0];
  const float* cdd   = (const float*)d_in[1];
  const float* cwt   = (const float*)d_in[2];
  const float* W_att = (const float*)d_in[3];
  const float* b_att = (const float*)d_in[4];
  const float* q_att = (const float*)d_in[5];
  const float* W_lin = (const float*)d_in[6];
  const float* b_lin = (const float*)d_in[7];
  const float* q_vec = (const float*)d_in[8];
  float* out = (float*)d_out;

  float* ws     = (float*)d_ws;
  float* logits = ws;                                   // B*K*H   = 51200
  float* u_b    = ws + (size_t)B_*K_*H_;                // B*K*D   = 204800
  float* ulin   = u_b + (size_t)B_*K_*D_;               // B*K*E   = 102400

  k1_att     <<<dim3((B_*H_)/64, K_), 256, 0, stream>>>(his, W_att, b_att, q_att, logits);
  k2_softmax_u<<<dim3(B_, K_),        256, 0, stream>>>(his, logits, u_b);
  k3_ulin    <<<dim3(B_, K_),         256, 0, stream>>>(u_b, W_lin, b_lin, ulin);
  k4_combine <<<N_/8,                 256, 0, stream>>>(cdd, cwt, W_lin, q_vec, u_b, ulin, out);
}